// Round 2
// baseline (144.071 us; speedup 1.0000x reference)
//
#include <hip/hip_runtime.h>

#define PNUM 128
#define BATCH 8192
#define NPAIR (2 * BATCH)          // 16384 (batch, pred) pairs
#define PAIRS_PER_BLOCK 8          // 32 lanes per pair, 256 threads/block
#define GRID1 (NPAIR / PAIRS_PER_BLOCK)

// smooth-L1 over both coords of a point pair, branchless:
// m = min(|d|,1):  0.5*m*m + (|d| - m)
__device__ __forceinline__ float sl1p(float2 p, float2 q) {
    float dx = p.x - q.x, dy = p.y - q.y;
    float ax = fabsf(dx), ay = fabsf(dy);
    float mx = fminf(ax, 1.0f), my = fminf(ay, 1.0f);
    return fmaf(0.5f * mx, mx, ax - mx) + fmaf(0.5f * my, my, ay - my);
}

// 32 lanes per (batch,pred) pair; lane k owns shifts {4k,4k+1,4k+2,4k+3}.
// Sliding register window of gt: per j, 1 new float2 read serves 4 terms
// (16B/term -> 2B/term of LDS traffic). VALU-bound by design (~41us floor).
__global__ __launch_bounds__(256) void match_stage1(
        const float* __restrict__ pred0,
        const float* __restrict__ pred1,
        const float* __restrict__ gt,
        float* __restrict__ ws) {
    __shared__ float2 sp[PAIRS_PER_BLOCK][PNUM];
    __shared__ float2 sg[PAIRS_PER_BLOCK][2 * PNUM];   // doubled: kills the %128

    const int t  = threadIdx.x;
    const int k  = t & 31;          // lane within pair
    const int lp = t >> 5;          // local pair 0..7
    const int pr = blockIdx.x * PAIRS_PER_BLOCK + lp;
    const int b  = pr >> 1;

    // ---- stage global -> LDS (float4 = 2 points per load) ----
    const float* predsel = (pr & 1) ? pred1 : pred0;
    const float4* pv4 = (const float4*)(predsel + (size_t)b * (PNUM * 2));
    const float4* gv4 = (const float4*)(gt      + (size_t)b * (PNUM * 2));
    float4* sp4 = (float4*)sp[lp];
    float4* sg4 = (float4*)sg[lp];
    sp4[k]      = pv4[k];
    sp4[k + 32] = pv4[k + 32];
    float4 gA = gv4[k], gB = gv4[k + 32];
    sg4[k]      = gA;  sg4[k + 32] = gB;   // first copy
    sg4[k + 64] = gA;  sg4[k + 96] = gB;   // wrap copy
    __syncthreads();

    const float2* g  = sg[lp];
    const float2* pp = sp[lp];

    float2 w0 = g[4 * k + 0], w1 = g[4 * k + 1], w2 = g[4 * k + 2], w3 = g[4 * k + 3];
    float a0 = 0.f, a1 = 0.f, a2 = 0.f, a3 = 0.f;

#pragma unroll 2
    for (int j = 0; j < PNUM; j += 4) {
        // next 4 window entries (contiguous 32B per lane -> 2x ds_read_b128)
        float2 w4 = g[4 * k + j + 4], w5 = g[4 * k + j + 5],
               w6 = g[4 * k + j + 6], w7 = g[4 * k + j + 7];
        // 4 pred points (uniform per half-wave -> broadcast reads)
        float2 p0 = pp[j], p1 = pp[j + 1], p2 = pp[j + 2], p3 = pp[j + 3];

        a0 += sl1p(p0, w0); a1 += sl1p(p0, w1); a2 += sl1p(p0, w2); a3 += sl1p(p0, w3);
        a0 += sl1p(p1, w1); a1 += sl1p(p1, w2); a2 += sl1p(p1, w3); a3 += sl1p(p1, w4);
        a0 += sl1p(p2, w2); a1 += sl1p(p2, w3); a2 += sl1p(p2, w4); a3 += sl1p(p2, w5);
        a0 += sl1p(p3, w3); a1 += sl1p(p3, w4); a2 += sl1p(p3, w5); a3 += sl1p(p3, w6);

        w0 = w4; w1 = w5; w2 = w6; w3 = w7;
    }

    // min over this lane's 4 shifts, then over the 32 lanes of the pair
    float r = fminf(fminf(a0, a1), fminf(a2, a3));
#pragma unroll
    for (int m = 16; m > 0; m >>= 1)
        r = fminf(r, __shfl_xor(r, m, 64));   // xor<=16 stays within the 32-lane group
    if (k == 0) ws[pr] = r;
}

// Sum 16384 per-pair mins -> scalar. 1024 threads, 16 independent loads each.
__global__ __launch_bounds__(1024) void match_stage2(
        const float* __restrict__ ws, float* __restrict__ out) {
    const int t = threadIdx.x;
    float s = 0.f;
#pragma unroll
    for (int q = 0; q < NPAIR / 1024; ++q) s += ws[t + q * 1024];
#pragma unroll
    for (int m = 32; m > 0; m >>= 1) s += __shfl_xor(s, m, 64);

    __shared__ float wsum[16];
    if ((t & 63) == 0) wsum[t >> 6] = s;
    __syncthreads();
    if (t == 0) {
        float tot = 0.f;
#pragma unroll
        for (int i = 0; i < 16; ++i) tot += wsum[i];
        // mean over j (1/PNUM), mean over batch (1/BATCH), avg of two preds (1/2)
        out[0] = tot * (1.0f / (2.0f * BATCH * PNUM));
    }
}

extern "C" void kernel_launch(void* const* d_in, const int* in_sizes, int n_in,
                              void* d_out, int out_size, void* d_ws, size_t ws_size,
                              hipStream_t stream) {
    const float* pred0 = (const float*)d_in[0];
    const float* pred1 = (const float*)d_in[1];
    const float* gt    = (const float*)d_in[2];
    float* out = (float*)d_out;
    float* ws  = (float*)d_ws;   // NPAIR floats = 64 KiB

    match_stage1<<<GRID1, 256, 0, stream>>>(pred0, pred1, gt, ws);
    match_stage2<<<1, 1024, 0, stream>>>(ws, out);
}